// Round 2
// baseline (202.069 us; speedup 1.0000x reference)
//
#include <hip/hip_runtime.h>
#include <hip/hip_bf16.h>
#include <stdint.h>

// Problem constants
#define M_TOK 2048   // B*S
#define N_OUT 4096   // OUT_F
#define K_IN  4096   // IN_F
#define GROUPSZ 128
#define NGRP  32

typedef signed char i8;
typedef int    intx4  __attribute__((ext_vector_type(4)));
typedef float  floatx4 __attribute__((ext_vector_type(4)));

#define AS1 __attribute__((address_space(1)))
#define AS3 __attribute__((address_space(3)))

// ---------------- Kernel 1: fused quantization pass (one dispatch).
// Blocks [0, 2048): quantize one row of x to int8 with per-row scale
//   s_x[n] = rowmax/127 (symmetric). w stays EXACT (ints in [-7,7]).
// Blocks [2048, 2048+4096): narrow w int32 -> int8 (exact), 16 elems/thread.
#define XQ_BLOCKS (M_TOK)                       // 2048, 256 thr = 1 row
#define WQ_BLOCKS (N_OUT * K_IN / 16 / 256)     // 4096

__global__ __launch_bounds__(256) void quant_kernel(
    const float* __restrict__ x, const int* __restrict__ wq,
    i8* __restrict__ xq, i8* __restrict__ wq8, float* __restrict__ sx) {
  __shared__ float red[4];
  int b = blockIdx.x;
  int tid = threadIdx.x;
  if (b < XQ_BLOCKS) {
    const float* xr = x + (size_t)b * K_IN;
    int e0 = tid * 16;
    float4 v0 = *(const float4*)(xr + e0);
    float4 v1 = *(const float4*)(xr + e0 + 4);
    float4 v2 = *(const float4*)(xr + e0 + 8);
    float4 v3 = *(const float4*)(xr + e0 + 12);
    float m = fabsf(v0.x);
    m = fmaxf(m, fabsf(v0.y)); m = fmaxf(m, fabsf(v0.z)); m = fmaxf(m, fabsf(v0.w));
    m = fmaxf(m, fabsf(v1.x)); m = fmaxf(m, fabsf(v1.y)); m = fmaxf(m, fabsf(v1.z)); m = fmaxf(m, fabsf(v1.w));
    m = fmaxf(m, fabsf(v2.x)); m = fmaxf(m, fabsf(v2.y)); m = fmaxf(m, fabsf(v2.z)); m = fmaxf(m, fabsf(v2.w));
    m = fmaxf(m, fabsf(v3.x)); m = fmaxf(m, fabsf(v3.y)); m = fmaxf(m, fabsf(v3.z)); m = fmaxf(m, fabsf(v3.w));
#pragma unroll
    for (int off = 32; off > 0; off >>= 1)
      m = fmaxf(m, __shfl_xor(m, off, 64));
    int lane = tid & 63, wv = tid >> 6;
    if (lane == 0) red[wv] = m;
    __syncthreads();
    m = fmaxf(fmaxf(red[0], red[1]), fmaxf(red[2], red[3]));
    float inv = (m > 0.f) ? 127.f / m : 0.f;
    union { i8 q[16]; int4 v; } u;
    u.q[0]  = (i8)(int)rintf(v0.x * inv); u.q[1]  = (i8)(int)rintf(v0.y * inv);
    u.q[2]  = (i8)(int)rintf(v0.z * inv); u.q[3]  = (i8)(int)rintf(v0.w * inv);
    u.q[4]  = (i8)(int)rintf(v1.x * inv); u.q[5]  = (i8)(int)rintf(v1.y * inv);
    u.q[6]  = (i8)(int)rintf(v1.z * inv); u.q[7]  = (i8)(int)rintf(v1.w * inv);
    u.q[8]  = (i8)(int)rintf(v2.x * inv); u.q[9]  = (i8)(int)rintf(v2.y * inv);
    u.q[10] = (i8)(int)rintf(v2.z * inv); u.q[11] = (i8)(int)rintf(v2.w * inv);
    u.q[12] = (i8)(int)rintf(v3.x * inv); u.q[13] = (i8)(int)rintf(v3.y * inv);
    u.q[14] = (i8)(int)rintf(v3.z * inv); u.q[15] = (i8)(int)rintf(v3.w * inv);
    *(int4*)(xq + (size_t)b * K_IN + e0) = u.v;
    if (tid == 0) sx[b] = m * (1.f / 127.f);
  } else {
    size_t t = (size_t)(b - XQ_BLOCKS) * 256 + tid;   // 1M threads
    size_t base = t * 16;
    const int* src = wq + base;
    int4 a0 = *(const int4*)(src);
    int4 a1 = *(const int4*)(src + 4);
    int4 a2 = *(const int4*)(src + 8);
    int4 a3 = *(const int4*)(src + 12);
    union { i8 q[16]; int4 v; } u;
    u.q[0]  = (i8)a0.x; u.q[1]  = (i8)a0.y; u.q[2]  = (i8)a0.z; u.q[3]  = (i8)a0.w;
    u.q[4]  = (i8)a1.x; u.q[5]  = (i8)a1.y; u.q[6]  = (i8)a1.z; u.q[7]  = (i8)a1.w;
    u.q[8]  = (i8)a2.x; u.q[9]  = (i8)a2.y; u.q[10] = (i8)a2.z; u.q[11] = (i8)a2.w;
    u.q[12] = (i8)a3.x; u.q[13] = (i8)a3.y; u.q[14] = (i8)a3.z; u.q[15] = (i8)a3.w;
    *(int4*)(wq8 + base) = u.v;
  }
}

// ---------------- Kernel 2: int8 GEMM with per-group fp32 rescale + bias.
// y[n,o] = s_x[n] * sum_g( s_w[g,o] * dot_i32(xq[n,g,:], w[o,g,:]) ) + bias[o]
//
// R9 (post-mortem of R8: 64x64 wave-tile LDS savings were real but halving
// the machine wave count + drain-to-zero barriers cost more; Occupancy 32->17):
//  - BM=256 x BN=128 x BK=64, 512 threads = 8 waves (4x2), wave-tile 64x64.
//    Grid (32,8) = 256 blocks = 1/CU, 8 waves/CU.
//  - T3+T4 pipeline: double-buffered LDS (2 x 24KB), counted vmcnt(3):
//    the 3 global_load_lds for tile t+1 stay in flight across BOTH raw
//    s_barriers and land during tile t's 16-MFMA compute phase (~650 cyc).
//    vmcnt never drains to 0 in the main loop (only last iter).
//  - Magic-bias rescale kept (C-init 0x4B400000; bitcast - 12582912.0f is
//    the exact (float)dot for |dot| <= 56896 << 2^22). s_w distributes
//    linearly over the two K=64 half-group partials -> same math as R7.
//  - XOR swizzle adapted to 4-chunk rows: LDS[row][c] holds global chunk
//    c ^ (row&3); read chunk = quad ^ (l16&3). Conflict-free: (row&1,
//    chunk) forms 8 classes x 8 lanes covering all 32 banks.
//  - sws (s_w tile, 16KB) in LDS; sx read at epilogue from global (L2-hot).
//    LDS total = 32K(A) + 16K(B) + 16K(sws) = 64KB.
#define BM 256
#define BN 128
#define BK 64
#define NT (K_IN / BK)   // 64

__global__ __launch_bounds__(512, 2) void gemm_i8_kernel(
    const i8* __restrict__ Aq, const i8* __restrict__ Bq,
    const float* __restrict__ sx, const float* __restrict__ sw,
    const float* __restrict__ bias, float* __restrict__ C) {
  __shared__ i8 As[2 * BM * BK];        // 32 KB (double-buffered)
  __shared__ i8 Bs[2 * BN * BK];        // 16 KB (double-buffered)
  __shared__ float sws[NGRP * BN];      // 16 KB: s_w[g][rowB0 + c]

  const int tid  = threadIdx.x;
  const int lane = tid & 63;
  const int wave = tid >> 6;       // 0..7
  const int quad = lane >> 4;      // 0..3
  const int l16  = lane & 15;
  const int bm = blockIdx.y;
  const int bn = blockIdx.x;
  const int wm = wave >> 1;        // 0..3 -> 64-row slab of 256
  const int wn = wave & 1;         // 0..1 -> 64-col slab of 128

  const int rowA0 = bm * BM;
  const int rowB0 = bn * BN;

  // Hoisted staging sources. A: 1024 chunks of 16B (2/thread); B: 512 (1/thread).
  // Global source column pre-swizzled: LDS linear pos (row, c) <- global chunk
  // c ^ (row&3) (involution; the read applies the same XOR).
  const int cA0 = tid, cA1 = 512 + tid, cB = tid;
  const i8* srcA0 = Aq + (size_t)(rowA0 + (cA0 >> 2)) * K_IN
                       + (((cA0 & 3) ^ ((cA0 >> 2) & 3)) << 4);
  const i8* srcA1 = Aq + (size_t)(rowA0 + (cA1 >> 2)) * K_IN
                       + (((cA1 & 3) ^ ((cA1 >> 2) & 3)) << 4);
  const i8* srcB0 = Bq + (size_t)(rowB0 + (cB >> 2)) * K_IN
                       + (((cB & 3) ^ ((cB >> 2) & 3)) << 4);
  // Wave-uniform LDS dests (HW adds lane*16).
  i8* dstA0 = As + (size_t)(wave * 64) * 16;
  i8* dstA1 = As + (size_t)(512 + wave * 64) * 16;
  i8* dstB0 = Bs + (size_t)(wave * 64) * 16;

  auto stage = [&](int buf, int t) {
    const size_t ko = (size_t)t * BK;
    __builtin_amdgcn_global_load_lds(
        (const AS1 void*)(srcA0 + ko),
        (AS3 void*)(dstA0 + (size_t)buf * (BM * BK)), 16, 0, 0);
    __builtin_amdgcn_global_load_lds(
        (const AS1 void*)(srcA1 + ko),
        (AS3 void*)(dstA1 + (size_t)buf * (BM * BK)), 16, 0, 0);
    __builtin_amdgcn_global_load_lds(
        (const AS1 void*)(srcB0 + ko),
        (AS3 void*)(dstB0 + (size_t)buf * (BN * BK)), 16, 0, 0);
  };

  // Prologue: issue tile-0 stage first so its latency hides under the sws
  // staging + the full drain of the one-time __syncthreads below.
  stage(0, 0);
  {
    int g = tid >> 4, c0 = (tid & 15) * 8;     // 512 thr x 8 floats = 4096
    const float* src = sw + (size_t)g * N_OUT + rowB0 + c0;
    float* dst = sws + g * BN + c0;
    *(float4*)(dst)     = *(const float4*)(src);
    *(float4*)(dst + 4) = *(const float4*)(src + 4);
  }
  __syncthreads();   // one-time full drain (sws visible; tile-0 loads landed)

  floatx4 master[4][4];
#pragma unroll
  for (int i = 0; i < 4; ++i)
#pragma unroll
    for (int j = 0; j < 4; ++j) master[i][j] = (floatx4)0.0f;

  const intx4 MAGICV = {0x4B400000, 0x4B400000, 0x4B400000, 0x4B400000};
  const float MAGICF = 12582912.0f;        // 1.5 * 2^23

  const int xk = (quad ^ (l16 & 3)) << 4;  // swizzled 16B k-chunk byte offset

  for (int t = 0; t < NT; ++t) {
    const int cur = t & 1;
    if (t + 1 < NT) {
      stage(cur ^ 1, t + 1);                 // 3 loads stay in flight
      asm volatile("s_waitcnt vmcnt(3)" ::: "memory");   // cur-tile landed
    } else {
      asm volatile("s_waitcnt vmcnt(0)" ::: "memory");   // final tile
    }
    __builtin_amdgcn_s_barrier();            // BARRIER_A: cur readable by all

    const i8* Ab = As + (size_t)cur * (BM * BK);
    const i8* Bb = Bs + (size_t)cur * (BN * BK);
    intx4 a[4], b[4];
#pragma unroll
    for (int i = 0; i < 4; ++i)
      a[i] = *(const intx4*)(Ab + (size_t)(wm * 64 + i * 16 + l16) * BK + xk);
#pragma unroll
    for (int j = 0; j < 4; ++j)
      b[j] = *(const intx4*)(Bb + (size_t)(wn * 64 + j * 16 + l16) * BK + xk);

    const int g = t >> 1;
    float swv[4];
#pragma unroll
    for (int j = 0; j < 4; ++j)
      swv[j] = sws[g * BN + wn * 64 + j * 16 + l16];

    asm volatile("s_waitcnt lgkmcnt(0)" ::: "memory");   // reads done
    __builtin_amdgcn_s_barrier();            // BARRIER_B: cur^1 overwritable

    // 16 independent MFMAs (K=64 = half group), magic-seeded; rescale is
    // pure f32 sub+fma. s_w applies linearly to half-group partials.
#pragma unroll
    for (int i = 0; i < 4; ++i)
#pragma unroll
      for (int j = 0; j < 4; ++j) {
        intx4 acc = __builtin_amdgcn_mfma_i32_16x16x64_i8(a[i], b[j], MAGICV, 0, 0, 0);
        master[i][j] += (__builtin_bit_cast(floatx4, acc) - MAGICF) * swv[j];
      }
  }

  // Epilogue: C/D layout col = lane&15 (n), row = quad*4 + reg (m).
  // y = master * s_x[row] + bias[col]. sx/bias from global (L2-hot).
#pragma unroll
  for (int i = 0; i < 4; ++i) {
    float4 sxv = *(const float4*)(sx + rowA0 + wm * 64 + i * 16 + quad * 4);
#pragma unroll
    for (int j = 0; j < 4; ++j) {
      int col = rowB0 + wn * 64 + j * 16 + l16;
      float bv = bias[col];
      int rloc = wm * 64 + i * 16 + quad * 4;
      C[(size_t)(rowA0 + rloc + 0) * N_OUT + col] = master[i][j][0] * sxv.x + bv;
      C[(size_t)(rowA0 + rloc + 1) * N_OUT + col] = master[i][j][1] * sxv.y + bv;
      C[(size_t)(rowA0 + rloc + 2) * N_OUT + col] = master[i][j][2] * sxv.z + bv;
      C[(size_t)(rowA0 + rloc + 3) * N_OUT + col] = master[i][j][3] * sxv.w + bv;
    }
  }
}

extern "C" void kernel_launch(void* const* d_in, const int* in_sizes, int n_in,
                              void* d_out, int out_size, void* d_ws, size_t ws_size,
                              hipStream_t stream) {
  const float* x    = (const float*)d_in[0];
  const int*   wq   = (const int*)d_in[1];     // integer input -> int32 per harness
  const float* sw   = (const float*)d_in[2];
  const float* bias = (const float*)d_in[3];
  float* out = (float*)d_out;

  i8*    xq  = (i8*)d_ws;                                          // 8 MB
  i8*    wq8 = (i8*)((char*)d_ws + (size_t)M_TOK * K_IN);          // 16 MB
  float* sx  = (float*)((char*)d_ws + (size_t)M_TOK * K_IN
                                     + (size_t)N_OUT * K_IN);      // 8 KB

  {
    int nblocks = XQ_BLOCKS + WQ_BLOCKS;        // 6144
    quant_kernel<<<nblocks, 256, 0, stream>>>(x, wq, xq, wq8, sx);
  }
  {
    dim3 grid(N_OUT / BN, M_TOK / BM);          // (32, 8) = 256 blocks
    gemm_i8_kernel<<<grid, 512, 0, stream>>>(xq, wq8, sx, sw, bias, out);
  }
}

// Round 3
// 184.087 us; speedup vs baseline: 1.0977x; 1.0977x over previous
//
#include <hip/hip_runtime.h>
#include <hip/hip_bf16.h>
#include <stdint.h>

// Problem constants
#define M_TOK 2048   // B*S
#define N_OUT 4096   // OUT_F
#define K_IN  4096   // IN_F
#define GROUPSZ 128
#define NGRP  32

typedef signed char i8;
typedef int    intx4  __attribute__((ext_vector_type(4)));
typedef float  floatx4 __attribute__((ext_vector_type(4)));

#define AS1 __attribute__((address_space(1)))
#define AS3 __attribute__((address_space(3)))

// ---------------- Kernel 1: fused quantization pass (one dispatch).
// Blocks [0, 2048): quantize one row of x to int8 with per-row scale
//   s_x[n] = rowmax/127 (symmetric). w stays EXACT (ints in [-7,7]).
// Blocks [2048, 2048+4096): narrow w int32 -> int8 (exact), 16 elems/thread.
#define XQ_BLOCKS (M_TOK)                       // 2048, 256 thr = 1 row
#define WQ_BLOCKS (N_OUT * K_IN / 16 / 256)     // 4096

__global__ __launch_bounds__(256) void quant_kernel(
    const float* __restrict__ x, const int* __restrict__ wq,
    i8* __restrict__ xq, i8* __restrict__ wq8, float* __restrict__ sx) {
  __shared__ float red[4];
  int b = blockIdx.x;
  int tid = threadIdx.x;
  if (b < XQ_BLOCKS) {
    const float* xr = x + (size_t)b * K_IN;
    int e0 = tid * 16;
    float4 v0 = *(const float4*)(xr + e0);
    float4 v1 = *(const float4*)(xr + e0 + 4);
    float4 v2 = *(const float4*)(xr + e0 + 8);
    float4 v3 = *(const float4*)(xr + e0 + 12);
    float m = fabsf(v0.x);
    m = fmaxf(m, fabsf(v0.y)); m = fmaxf(m, fabsf(v0.z)); m = fmaxf(m, fabsf(v0.w));
    m = fmaxf(m, fabsf(v1.x)); m = fmaxf(m, fabsf(v1.y)); m = fmaxf(m, fabsf(v1.z)); m = fmaxf(m, fabsf(v1.w));
    m = fmaxf(m, fabsf(v2.x)); m = fmaxf(m, fabsf(v2.y)); m = fmaxf(m, fabsf(v2.z)); m = fmaxf(m, fabsf(v2.w));
    m = fmaxf(m, fabsf(v3.x)); m = fmaxf(m, fabsf(v3.y)); m = fmaxf(m, fabsf(v3.z)); m = fmaxf(m, fabsf(v3.w));
#pragma unroll
    for (int off = 32; off > 0; off >>= 1)
      m = fmaxf(m, __shfl_xor(m, off, 64));
    int lane = tid & 63, wv = tid >> 6;
    if (lane == 0) red[wv] = m;
    __syncthreads();
    m = fmaxf(fmaxf(red[0], red[1]), fmaxf(red[2], red[3]));
    float inv = (m > 0.f) ? 127.f / m : 0.f;
    union { i8 q[16]; int4 v; } u;
    u.q[0]  = (i8)(int)rintf(v0.x * inv); u.q[1]  = (i8)(int)rintf(v0.y * inv);
    u.q[2]  = (i8)(int)rintf(v0.z * inv); u.q[3]  = (i8)(int)rintf(v0.w * inv);
    u.q[4]  = (i8)(int)rintf(v1.x * inv); u.q[5]  = (i8)(int)rintf(v1.y * inv);
    u.q[6]  = (i8)(int)rintf(v1.z * inv); u.q[7]  = (i8)(int)rintf(v1.w * inv);
    u.q[8]  = (i8)(int)rintf(v2.x * inv); u.q[9]  = (i8)(int)rintf(v2.y * inv);
    u.q[10] = (i8)(int)rintf(v2.z * inv); u.q[11] = (i8)(int)rintf(v2.w * inv);
    u.q[12] = (i8)(int)rintf(v3.x * inv); u.q[13] = (i8)(int)rintf(v3.y * inv);
    u.q[14] = (i8)(int)rintf(v3.z * inv); u.q[15] = (i8)(int)rintf(v3.w * inv);
    *(int4*)(xq + (size_t)b * K_IN + e0) = u.v;
    if (tid == 0) sx[b] = m * (1.f / 127.f);
  } else {
    size_t t = (size_t)(b - XQ_BLOCKS) * 256 + tid;   // 1M threads
    size_t base = t * 16;
    const int* src = wq + base;
    int4 a0 = *(const int4*)(src);
    int4 a1 = *(const int4*)(src + 4);
    int4 a2 = *(const int4*)(src + 8);
    int4 a3 = *(const int4*)(src + 12);
    union { i8 q[16]; int4 v; } u;
    u.q[0]  = (i8)a0.x; u.q[1]  = (i8)a0.y; u.q[2]  = (i8)a0.z; u.q[3]  = (i8)a0.w;
    u.q[4]  = (i8)a1.x; u.q[5]  = (i8)a1.y; u.q[6]  = (i8)a1.z; u.q[7]  = (i8)a1.w;
    u.q[8]  = (i8)a2.x; u.q[9]  = (i8)a2.y; u.q[10] = (i8)a2.z; u.q[11] = (i8)a2.w;
    u.q[12] = (i8)a3.x; u.q[13] = (i8)a3.y; u.q[14] = (i8)a3.z; u.q[15] = (i8)a3.w;
    *(int4*)(wq8 + base) = u.v;
  }
}

// ---------------- Kernel 2: int8 GEMM with per-group fp32 rescale + bias.
// y[n,o] = s_x[n] * sum_g( s_w[g,o] * dot_i32(xq[n,g,:], w[o,g,:]) ) + bias[o]
//
// R10 (post-mortem of R9: BK=64's 2-bit XOR on 64B rows aliased within lane
// octets -> SQ_LDS_BANK_CONFLICT 196K->4.23M, +4 cyc per ds_read_b128.
// Keep R9's pipeline, revert LDS geometry to the R8-VERIFIED conflict-free
// one: 128B rows + 3-bit XOR, octet covers all 8 bank-groups exactly once):
//  - BM=256 x BN=128 x BK=128 (= GROUPSZ: one K-step == one quant group).
//    512 threads = 8 waves (4x2), wave-tile 64x64, grid (32,8) = 256 blocks.
//  - Double-buffered LDS (A 2x32K, B 2x16K, sws 16K = 112KB, 1 block/CU).
//    Counted vmcnt(6): tile t+1's 6 global_load_lds stay in flight across
//    both s_barriers, landing under tile t's 32-MFMA compute (~650+ cyc).
//    vmcnt never drains to 0 in the main loop.
//  - Magic-bias rescale (C-init 0x4B400000; bitcast - 12582912.0f is the
//    exact (float)dot, |dot| <= 113792 << 2^22). Bit-identical numerics.
//  - Swizzle: LDS row r (128B) holds global 16B-chunk c at col c ^ (r&7);
//    read col (s*4+quad) ^ (l16&7). R8-measured: ~196K conflicts (clean).
#define BM 256
#define BN 128
#define BK 128
#define NT (K_IN / BK)   // 32

__global__ __launch_bounds__(512, 2) void gemm_i8_kernel(
    const i8* __restrict__ Aq, const i8* __restrict__ Bq,
    const float* __restrict__ sx, const float* __restrict__ sw,
    const float* __restrict__ bias, float* __restrict__ C) {
  __shared__ i8 As[2 * BM * BK];        // 64 KB (double-buffered)
  __shared__ i8 Bs[2 * BN * BK];        // 32 KB (double-buffered)
  __shared__ float sws[NGRP * BN];      // 16 KB: s_w[g][rowB0 + c]

  const int tid  = threadIdx.x;
  const int lane = tid & 63;
  const int wave = tid >> 6;       // 0..7
  const int quad = lane >> 4;      // 0..3
  const int l16  = lane & 15;
  const int bm = blockIdx.y;
  const int bn = blockIdx.x;
  const int wm = wave >> 1;        // 0..3 -> 64-row slab of 256
  const int wn = wave & 1;         // 0..1 -> 64-col slab of 128

  const int rowA0 = bm * BM;
  const int rowB0 = bn * BN;

  // Hoisted staging sources. A: 2048 16B-chunks (4/thread); B: 1024 (2/thread).
  // Global source chunk-col pre-swizzled (involution c ^= row&7); LDS dest is
  // linear (global_load_lds constraint), the read applies the same XOR.
  const i8* srcA[4]; const i8* srcB[2];
#pragma unroll
  for (int i = 0; i < 4; ++i) {
    int chunk = i * 512 + tid;              // 0..2047
    int row = chunk >> 3;                   // 0..255
    int csw = (chunk & 7) ^ (row & 7);
    srcA[i] = Aq + (size_t)(rowA0 + row) * K_IN + (csw << 4);
  }
#pragma unroll
  for (int i = 0; i < 2; ++i) {
    int chunk = i * 512 + tid;              // 0..1023
    int row = chunk >> 3;                   // 0..127
    int csw = (chunk & 7) ^ (row & 7);
    srcB[i] = Bq + (size_t)(rowB0 + row) * K_IN + (csw << 4);
  }
  // Wave-uniform LDS dests (HW adds lane*16).
  i8* dstA[4]; i8* dstB[2];
#pragma unroll
  for (int i = 0; i < 4; ++i) dstA[i] = As + (size_t)(i * 512 + wave * 64) * 16;
#pragma unroll
  for (int i = 0; i < 2; ++i) dstB[i] = Bs + (size_t)(i * 512 + wave * 64) * 16;

  auto stage = [&](int buf, int t) {
    const size_t ko = (size_t)t * BK;
#pragma unroll
    for (int i = 0; i < 4; ++i)
      __builtin_amdgcn_global_load_lds(
          (const AS1 void*)(srcA[i] + ko),
          (AS3 void*)(dstA[i] + (size_t)buf * (BM * BK)), 16, 0, 0);
#pragma unroll
    for (int i = 0; i < 2; ++i)
      __builtin_amdgcn_global_load_lds(
          (const AS1 void*)(srcB[i] + ko),
          (AS3 void*)(dstB[i] + (size_t)buf * (BN * BK)), 16, 0, 0);
  };

  // Prologue: issue tile-0 stage first; its latency hides under sws staging
  // and the one-time full-drain __syncthreads.
  stage(0, 0);
  {
    int g = tid >> 4, c0 = (tid & 15) * 8;     // 512 thr x 8 floats = 4096
    const float* src = sw + (size_t)g * N_OUT + rowB0 + c0;
    float* dst = sws + g * BN + c0;
    *(float4*)(dst)     = *(const float4*)(src);
    *(float4*)(dst + 4) = *(const float4*)(src + 4);
  }
  __syncthreads();   // one-time full drain (sws visible; tile-0 landed)

  floatx4 master[4][4];
#pragma unroll
  for (int i = 0; i < 4; ++i)
#pragma unroll
    for (int j = 0; j < 4; ++j) master[i][j] = (floatx4)0.0f;

  const intx4 MAGICV = {0x4B400000, 0x4B400000, 0x4B400000, 0x4B400000};
  const float MAGICF = 12582912.0f;        // 1.5 * 2^23

  const int h  = l16 & 7;
  const int x0 = (quad ^ h) << 4;          // byte offset, k-chunk s=0
  const int x1 = x0 ^ 64;                  // s=1 (chunk ^ 4)

  for (int t = 0; t < NT; ++t) {
    const int cur = t & 1;
    if (t + 1 < NT) {
      stage(cur ^ 1, t + 1);                 // 6 loads stay in flight
      asm volatile("s_waitcnt vmcnt(6)" ::: "memory");   // cur tile landed
    } else {
      asm volatile("s_waitcnt vmcnt(0)" ::: "memory");   // final tile
    }
    __builtin_amdgcn_s_barrier();            // BARRIER_A: cur readable by all

    const i8* Ab = As + (size_t)cur * (BM * BK);
    const i8* Bb = Bs + (size_t)cur * (BN * BK);
    intx4 a[4][2], b[4][2];
#pragma unroll
    for (int i = 0; i < 4; ++i) {
      const i8* pa = Ab + (size_t)(wm * 64 + i * 16 + l16) * BK;
      a[i][0] = *(const intx4*)(pa + x0);
      a[i][1] = *(const intx4*)(pa + x1);
    }
#pragma unroll
    for (int j = 0; j < 4; ++j) {
      const i8* pb = Bb + (size_t)(wn * 64 + j * 16 + l16) * BK;
      b[j][0] = *(const intx4*)(pb + x0);
      b[j][1] = *(const intx4*)(pb + x1);
    }

    float swv[4];
#pragma unroll
    for (int j = 0; j < 4; ++j)
      swv[j] = sws[t * BN + wn * 64 + j * 16 + l16];

    asm volatile("s_waitcnt lgkmcnt(0)" ::: "memory");   // reads done
    __builtin_amdgcn_s_barrier();            // BARRIER_B: other buf writable

    // 16 frag-chains: 2 dependent MFMAs each (K=128 = one quant group),
    // C seeded with MAGIC so int->float conversion is a free bitcast.
#pragma unroll
    for (int i = 0; i < 4; ++i)
#pragma unroll
      for (int j = 0; j < 4; ++j) {
        intx4 acc = __builtin_amdgcn_mfma_i32_16x16x64_i8(a[i][0], b[j][0], MAGICV, 0, 0, 0);
        acc = __builtin_amdgcn_mfma_i32_16x16x64_i8(a[i][1], b[j][1], acc, 0, 0, 0);
        master[i][j] += (__builtin_bit_cast(floatx4, acc) - MAGICF) * swv[j];
      }
  }

  // Epilogue: C/D layout col = lane&15 (n), row = quad*4 + reg (m).
  // y = master * s_x[row] + bias[col]. sx/bias from global (L2-hot).
#pragma unroll
  for (int i = 0; i < 4; ++i) {
    float4 sxv = *(const float4*)(sx + rowA0 + wm * 64 + i * 16 + quad * 4);
#pragma unroll
    for (int j = 0; j < 4; ++j) {
      int col = rowB0 + wn * 64 + j * 16 + l16;
      float bv = bias[col];
      int rloc = wm * 64 + i * 16 + quad * 4;
      C[(size_t)(rowA0 + rloc + 0) * N_OUT + col] = master[i][j][0] * sxv.x + bv;
      C[(size_t)(rowA0 + rloc + 1) * N_OUT + col] = master[i][j][1] * sxv.y + bv;
      C[(size_t)(rowA0 + rloc + 2) * N_OUT + col] = master[i][j][2] * sxv.z + bv;
      C[(size_t)(rowA0 + rloc + 3) * N_OUT + col] = master[i][j][3] * sxv.w + bv;
    }
  }
}

extern "C" void kernel_launch(void* const* d_in, const int* in_sizes, int n_in,
                              void* d_out, int out_size, void* d_ws, size_t ws_size,
                              hipStream_t stream) {
  const float* x    = (const float*)d_in[0];
  const int*   wq   = (const int*)d_in[1];     // integer input -> int32 per harness
  const float* sw   = (const float*)d_in[2];
  const float* bias = (const float*)d_in[3];
  float* out = (float*)d_out;

  i8*    xq  = (i8*)d_ws;                                          // 8 MB
  i8*    wq8 = (i8*)((char*)d_ws + (size_t)M_TOK * K_IN);          // 16 MB
  float* sx  = (float*)((char*)d_ws + (size_t)M_TOK * K_IN
                                     + (size_t)N_OUT * K_IN);      // 8 KB

  {
    int nblocks = XQ_BLOCKS + WQ_BLOCKS;        // 6144
    quant_kernel<<<nblocks, 256, 0, stream>>>(x, wq, xq, wq8, sx);
  }
  {
    dim3 grid(N_OUT / BN, M_TOK / BM);          // (32, 8) = 256 blocks
    gemm_i8_kernel<<<grid, 512, 0, stream>>>(xq, wq8, sx, sw, bias, out);
  }
}

// Round 4
// 179.395 us; speedup vs baseline: 1.1264x; 1.0262x over previous
//
#include <hip/hip_runtime.h>
#include <hip/hip_bf16.h>
#include <stdint.h>

// Problem constants
#define M_TOK 2048   // B*S
#define N_OUT 4096   // OUT_F
#define K_IN  4096   // IN_F
#define GROUPSZ 128
#define NGRP  32

typedef signed char i8;
typedef int    intx4  __attribute__((ext_vector_type(4)));
typedef float  floatx4 __attribute__((ext_vector_type(4)));

#define AS1 __attribute__((address_space(1)))
#define AS3 __attribute__((address_space(3)))

// ---------------- Kernel 1: fused quantization pass (one dispatch).
// Blocks [0, 2048): quantize one row of x to int8 with per-row scale
//   s_x[n] = rowmax/127 (symmetric). w stays EXACT (ints in [-7,7]).
// Blocks [2048, 2048+4096): narrow w int32 -> int8 (exact), 16 elems/thread.
#define XQ_BLOCKS (M_TOK)                       // 2048, 256 thr = 1 row
#define WQ_BLOCKS (N_OUT * K_IN / 16 / 256)     // 4096

__global__ __launch_bounds__(256) void quant_kernel(
    const float* __restrict__ x, const int* __restrict__ wq,
    i8* __restrict__ xq, i8* __restrict__ wq8, float* __restrict__ sx) {
  __shared__ float red[4];
  int b = blockIdx.x;
  int tid = threadIdx.x;
  if (b < XQ_BLOCKS) {
    const float* xr = x + (size_t)b * K_IN;
    int e0 = tid * 16;
    float4 v0 = *(const float4*)(xr + e0);
    float4 v1 = *(const float4*)(xr + e0 + 4);
    float4 v2 = *(const float4*)(xr + e0 + 8);
    float4 v3 = *(const float4*)(xr + e0 + 12);
    float m = fabsf(v0.x);
    m = fmaxf(m, fabsf(v0.y)); m = fmaxf(m, fabsf(v0.z)); m = fmaxf(m, fabsf(v0.w));
    m = fmaxf(m, fabsf(v1.x)); m = fmaxf(m, fabsf(v1.y)); m = fmaxf(m, fabsf(v1.z)); m = fmaxf(m, fabsf(v1.w));
    m = fmaxf(m, fabsf(v2.x)); m = fmaxf(m, fabsf(v2.y)); m = fmaxf(m, fabsf(v2.z)); m = fmaxf(m, fabsf(v2.w));
    m = fmaxf(m, fabsf(v3.x)); m = fmaxf(m, fabsf(v3.y)); m = fmaxf(m, fabsf(v3.z)); m = fmaxf(m, fabsf(v3.w));
#pragma unroll
    for (int off = 32; off > 0; off >>= 1)
      m = fmaxf(m, __shfl_xor(m, off, 64));
    int lane = tid & 63, wv = tid >> 6;
    if (lane == 0) red[wv] = m;
    __syncthreads();
    m = fmaxf(fmaxf(red[0], red[1]), fmaxf(red[2], red[3]));
    float inv = (m > 0.f) ? 127.f / m : 0.f;
    union { i8 q[16]; int4 v; } u;
    u.q[0]  = (i8)(int)rintf(v0.x * inv); u.q[1]  = (i8)(int)rintf(v0.y * inv);
    u.q[2]  = (i8)(int)rintf(v0.z * inv); u.q[3]  = (i8)(int)rintf(v0.w * inv);
    u.q[4]  = (i8)(int)rintf(v1.x * inv); u.q[5]  = (i8)(int)rintf(v1.y * inv);
    u.q[6]  = (i8)(int)rintf(v1.z * inv); u.q[7]  = (i8)(int)rintf(v1.w * inv);
    u.q[8]  = (i8)(int)rintf(v2.x * inv); u.q[9]  = (i8)(int)rintf(v2.y * inv);
    u.q[10] = (i8)(int)rintf(v2.z * inv); u.q[11] = (i8)(int)rintf(v2.w * inv);
    u.q[12] = (i8)(int)rintf(v3.x * inv); u.q[13] = (i8)(int)rintf(v3.y * inv);
    u.q[14] = (i8)(int)rintf(v3.z * inv); u.q[15] = (i8)(int)rintf(v3.w * inv);
    *(int4*)(xq + (size_t)b * K_IN + e0) = u.v;
    if (tid == 0) sx[b] = m * (1.f / 127.f);
  } else {
    size_t t = (size_t)(b - XQ_BLOCKS) * 256 + tid;   // 1M threads
    size_t base = t * 16;
    const int* src = wq + base;
    int4 a0 = *(const int4*)(src);
    int4 a1 = *(const int4*)(src + 4);
    int4 a2 = *(const int4*)(src + 8);
    int4 a3 = *(const int4*)(src + 12);
    union { i8 q[16]; int4 v; } u;
    u.q[0]  = (i8)a0.x; u.q[1]  = (i8)a0.y; u.q[2]  = (i8)a0.z; u.q[3]  = (i8)a0.w;
    u.q[4]  = (i8)a1.x; u.q[5]  = (i8)a1.y; u.q[6]  = (i8)a1.z; u.q[7]  = (i8)a1.w;
    u.q[8]  = (i8)a2.x; u.q[9]  = (i8)a2.y; u.q[10] = (i8)a2.z; u.q[11] = (i8)a2.w;
    u.q[12] = (i8)a3.x; u.q[13] = (i8)a3.y; u.q[14] = (i8)a3.z; u.q[15] = (i8)a3.w;
    *(int4*)(wq8 + base) = u.v;
  }
}

// ---------------- Kernel 2: int8 GEMM with per-group fp32 rescale + bias.
// y[n,o] = s_x[n] * sum_g( s_w[g,o] * dot_i32(xq[n,g,:], w[o,g,:]) ) + bias[o]
//
// R11 (post-mortem of R10: conflicts fixed at 32K but 1 block/CU + mid-iter
// lgkmcnt(0)+barrier lock-stepped all 8 waves -> DS phase and MFMA phase
// serialized CU-wide, 4900 cyc/K-step vs ~2850 floor sum. R7 beat it via
// 2 co-resident blocks overlapping phases):
//  - BM=BN=128, 256 thr = 4 waves of 64x64 (R8-verified decomposition),
//    double-buffered LDS A 2x16K + B 2x16K = 64KB -> 2 blocks/CU. The two
//    blocks' barrier domains are independent: one block's MFMA phase covers
//    the other's stage/DS phase.
//  - Counted vmcnt kept (8 global_load_lds + 4 prefetched s_w dword loads
//    per thread per step -> vmcnt(12); never drains to 0 in-loop).
//  - BARRIER_B moved to END of iteration (where buffer protection actually
//    needs it): compiler's fine-grained lgkmcnt interleaves ds_read+MFMA.
//  - s_w out of LDS: 4 dword loads/wave/iter from L2, prefetched one iter
//    ahead into regs (swv_cur/swv_nxt).
//  - Magic-bias rescale (C-init 0x4B400000; bitcast - 12582912.0f exact,
//    |dot| <= 113792 << 2^22). Swizzle: R10-verified (32K conflicts): LDS
//    row r holds chunk c at col c^(r&7); read col (s*4+quad)^(l16&7).
#define BM 128
#define BN 128
#define BK 128
#define NT (K_IN / BK)   // 32

__global__ __launch_bounds__(256, 2) void gemm_i8_kernel(
    const i8* __restrict__ Aq, const i8* __restrict__ Bq,
    const float* __restrict__ sx, const float* __restrict__ sw,
    const float* __restrict__ bias, float* __restrict__ C) {
  __shared__ i8 As[2 * BM * BK];        // 32 KB (double-buffered)
  __shared__ i8 Bs[2 * BN * BK];        // 32 KB (double-buffered)

  const int tid  = threadIdx.x;
  const int lane = tid & 63;
  const int wave = tid >> 6;       // 0..3
  const int quad = lane >> 4;      // 0..3
  const int l16  = lane & 15;
  const int bm = blockIdx.y;
  const int bn = blockIdx.x;
  const int wm = wave >> 1;        // 0..1 -> 64-row slab of 128
  const int wn = wave & 1;         // 0..1 -> 64-col slab of 128

  const int rowA0 = bm * BM;
  const int rowB0 = bn * BN;

  // Hoisted staging sources: 1024 16B-chunks per matrix, 4 per thread.
  // Global source chunk-col pre-swizzled (involution c ^= row&7); LDS dest
  // linear (global_load_lds constraint); reads apply the same XOR.
  const i8* srcA[4]; const i8* srcB[4];
#pragma unroll
  for (int i = 0; i < 4; ++i) {
    int chunk = i * 256 + tid;              // 0..1023
    int row = chunk >> 3;                   // 0..127
    int csw = (chunk & 7) ^ (row & 7);
    srcA[i] = Aq + (size_t)(rowA0 + row) * K_IN + (csw << 4);
    srcB[i] = Bq + (size_t)(rowB0 + row) * K_IN + (csw << 4);
  }
  // Wave-uniform LDS dests (HW adds lane*16).
  i8* dstA[4]; i8* dstB[4];
#pragma unroll
  for (int i = 0; i < 4; ++i) {
    dstA[i] = As + (size_t)(i * 256 + wave * 64) * 16;
    dstB[i] = Bs + (size_t)(i * 256 + wave * 64) * 16;
  }

  auto stage = [&](int buf, int t) {
    const size_t ko = (size_t)t * BK;
#pragma unroll
    for (int i = 0; i < 4; ++i)
      __builtin_amdgcn_global_load_lds(
          (const AS1 void*)(srcA[i] + ko),
          (AS3 void*)(dstA[i] + (size_t)buf * (BM * BK)), 16, 0, 0);
#pragma unroll
    for (int i = 0; i < 4; ++i)
      __builtin_amdgcn_global_load_lds(
          (const AS1 void*)(srcB[i] + ko),
          (AS3 void*)(dstB[i] + (size_t)buf * (BN * BK)), 16, 0, 0);
  };

  // s_w pointers for this wave's 4 column frags (g advances by +N_OUT/step).
  const float* swp = sw + rowB0 + wn * 64 + l16;

  // Prologue: tile-0 stage + s_w(t=0) prefetch; one-time full drain.
  stage(0, 0);
  float swv_cur[4], swv_nxt[4];
#pragma unroll
  for (int j = 0; j < 4; ++j) swv_cur[j] = swp[j * 16];
  __syncthreads();   // drains vmcnt+lgkmcnt: tile 0 + sw(0) landed

  floatx4 master[4][4];
#pragma unroll
  for (int i = 0; i < 4; ++i)
#pragma unroll
    for (int j = 0; j < 4; ++j) master[i][j] = (floatx4)0.0f;

  const intx4 MAGICV = {0x4B400000, 0x4B400000, 0x4B400000, 0x4B400000};
  const float MAGICF = 12582912.0f;        // 1.5 * 2^23

  const int h  = l16 & 7;
  const int x0 = (quad ^ h) << 4;          // byte offset, k-chunk s=0
  const int x1 = x0 ^ 64;                  // s=1 (chunk ^ 4)

  for (int t = 0; t < NT; ++t) {
    const int cur = t & 1;
    if (t + 1 < NT) {
      stage(cur ^ 1, t + 1);               // 8 loads stay in flight
#pragma unroll
      for (int j = 0; j < 4; ++j)          // 4 more: s_w for t+1 (L2-hot)
        swv_nxt[j] = swp[(size_t)(t + 1) * N_OUT + j * 16];
      asm volatile("s_waitcnt vmcnt(12)" ::: "memory");  // tile t landed
    } else {
      asm volatile("s_waitcnt vmcnt(0)" ::: "memory");   // final tile
    }
    __builtin_amdgcn_s_barrier();          // BARRIER_A: cur readable by all

    const i8* Ab = As + (size_t)cur * (BM * BK);
    const i8* Bb = Bs + (size_t)cur * (BN * BK);
    intx4 a[4][2], b[4][2];
#pragma unroll
    for (int i = 0; i < 4; ++i) {
      const i8* pa = Ab + (size_t)(wm * 64 + i * 16 + l16) * BK;
      a[i][0] = *(const intx4*)(pa + x0);
      a[i][1] = *(const intx4*)(pa + x1);
    }
#pragma unroll
    for (int j = 0; j < 4; ++j) {
      const i8* pb = Bb + (size_t)(wn * 64 + j * 16 + l16) * BK;
      b[j][0] = *(const intx4*)(pb + x0);
      b[j][1] = *(const intx4*)(pb + x1);
    }

    // 16 frag-chains: 2 dependent MFMAs each (K=128 = one quant group),
    // magic-seeded so int->float is a free bitcast. Compiler inserts
    // fine-grained lgkmcnt between ds_reads and MFMAs (no manual drain
    // here -> ds_read/MFMA interleave + wave skew until BARRIER_B).
#pragma unroll
    for (int i = 0; i < 4; ++i)
#pragma unroll
      for (int j = 0; j < 4; ++j) {
        intx4 acc = __builtin_amdgcn_mfma_i32_16x16x64_i8(a[i][0], b[j][0], MAGICV, 0, 0, 0);
        acc = __builtin_amdgcn_mfma_i32_16x16x64_i8(a[i][1], b[j][1], acc, 0, 0, 0);
        master[i][j] += (__builtin_bit_cast(floatx4, acc) - MAGICF) * swv_cur[j];
      }
#pragma unroll
    for (int j = 0; j < 4; ++j) swv_cur[j] = swv_nxt[j];

    // Buffer protection: all waves' ds_reads of buf cur must complete
    // before any wave stages into buf cur at iter t+1.
    asm volatile("s_waitcnt lgkmcnt(0)" ::: "memory");
    __builtin_amdgcn_s_barrier();          // BARRIER_B (end of iteration)
  }

  // Epilogue: C/D layout col = lane&15 (n), row = quad*4 + reg (m).
  // y = master * s_x[row] + bias[col]. sx/bias from global (L2-hot).
#pragma unroll
  for (int i = 0; i < 4; ++i) {
    float4 sxv = *(const float4*)(sx + rowA0 + wm * 64 + i * 16 + quad * 4);
#pragma unroll
    for (int j = 0; j < 4; ++j) {
      int col = rowB0 + wn * 64 + j * 16 + l16;
      float bv = bias[col];
      int rloc = wm * 64 + i * 16 + quad * 4;
      C[(size_t)(rowA0 + rloc + 0) * N_OUT + col] = master[i][j][0] * sxv.x + bv;
      C[(size_t)(rowA0 + rloc + 1) * N_OUT + col] = master[i][j][1] * sxv.y + bv;
      C[(size_t)(rowA0 + rloc + 2) * N_OUT + col] = master[i][j][2] * sxv.z + bv;
      C[(size_t)(rowA0 + rloc + 3) * N_OUT + col] = master[i][j][3] * sxv.w + bv;
    }
  }
}

extern "C" void kernel_launch(void* const* d_in, const int* in_sizes, int n_in,
                              void* d_out, int out_size, void* d_ws, size_t ws_size,
                              hipStream_t stream) {
  const float* x    = (const float*)d_in[0];
  const int*   wq   = (const int*)d_in[1];     // integer input -> int32 per harness
  const float* sw   = (const float*)d_in[2];
  const float* bias = (const float*)d_in[3];
  float* out = (float*)d_out;

  i8*    xq  = (i8*)d_ws;                                          // 8 MB
  i8*    wq8 = (i8*)((char*)d_ws + (size_t)M_TOK * K_IN);          // 16 MB
  float* sx  = (float*)((char*)d_ws + (size_t)M_TOK * K_IN
                                     + (size_t)N_OUT * K_IN);      // 8 KB

  {
    int nblocks = XQ_BLOCKS + WQ_BLOCKS;        // 6144
    quant_kernel<<<nblocks, 256, 0, stream>>>(x, wq, xq, wq8, sx);
  }
  {
    dim3 grid(N_OUT / BN, M_TOK / BM);          // (32, 16) = 512 blocks
    gemm_i8_kernel<<<grid, 256, 0, stream>>>(xq, wq8, sx, sw, bias, out);
  }
}